// Round 8
// baseline (5793.921 us; speedup 1.0000x reference)
//
#include <hip/hip_runtime.h>

#define N_NODES 100000
#define N_EDGES 600000
#define NUM_GRAPHS 256

#define SCAN_BS   256
#define SCAN_CH   4
#define SCAN_CHUNK (SCAN_BS * SCAN_CH)                      // 1024
#define SCAN_NB   ((N_NODES + SCAN_CHUNK - 1) / SCAN_CHUNK) // 98

// ===========================================================================
// CSR build: histogram -> 3-phase scan -> fill (once per launch, reused 5x)
// ===========================================================================
__global__ void hist_kernel(const int* __restrict__ dst, int* __restrict__ deg) {
    int e = blockIdx.x * blockDim.x + threadIdx.x;
    if (e < N_EDGES) atomicAdd(&deg[dst[e]], 1);
}

__global__ void scan_p1_kernel(const int* __restrict__ deg, int* __restrict__ bsum) {
    __shared__ int sh[SCAN_BS];
    const int b = blockIdx.x, t = threadIdx.x;
    const int base = b * SCAN_CHUNK + t * SCAN_CH;
    int s = 0;
    #pragma unroll
    for (int k = 0; k < SCAN_CH; ++k) {
        int i = base + k;
        if (i < N_NODES) s += deg[i];
    }
    sh[t] = s;
    __syncthreads();
    for (int off = SCAN_BS / 2; off > 0; off >>= 1) {
        if (t < off) sh[t] += sh[t + off];
        __syncthreads();
    }
    if (t == 0) bsum[b] = sh[0];
}

__global__ void scan_p2_kernel(int* __restrict__ bsum, int* __restrict__ rowptr) {
    __shared__ int sh[128];
    const int t = threadIdx.x;
    int v = (t < SCAN_NB) ? bsum[t] : 0;
    sh[t] = v;
    __syncthreads();
    for (int off = 1; off < 128; off <<= 1) {
        int u = (t >= off) ? sh[t - off] : 0;
        __syncthreads();
        sh[t] += u;
        __syncthreads();
    }
    if (t < SCAN_NB) bsum[t] = sh[t] - v;
    if (t == 0) rowptr[N_NODES] = N_EDGES;
}

__global__ void scan_p3_kernel(const int* __restrict__ deg, const int* __restrict__ bsum,
                               int* __restrict__ rowptr, int* __restrict__ cursor) {
    __shared__ int sh[SCAN_BS];
    const int b = blockIdx.x, t = threadIdx.x;
    const int base = b * SCAN_CHUNK + t * SCAN_CH;
    int v[SCAN_CH];
    int s = 0;
    #pragma unroll
    for (int k = 0; k < SCAN_CH; ++k) {
        int i = base + k;
        v[k] = (i < N_NODES) ? deg[i] : 0;
        s += v[k];
    }
    sh[t] = s;
    __syncthreads();
    for (int off = 1; off < SCAN_BS; off <<= 1) {
        int u = (t >= off) ? sh[t - off] : 0;
        __syncthreads();
        sh[t] += u;
        __syncthreads();
    }
    int run = bsum[b] + sh[t] - s;
    #pragma unroll
    for (int k = 0; k < SCAN_CH; ++k) {
        int i = base + k;
        if (i < N_NODES) { rowptr[i] = run; cursor[i] = run; }
        run += v[k];
    }
}

__global__ void fill_kernel(const int* __restrict__ src, const int* __restrict__ dst,
                            const float* __restrict__ w, int* __restrict__ cursor,
                            int* __restrict__ ssrc, float* __restrict__ sw) {
    int e = blockIdx.x * blockDim.x + threadIdx.x;
    if (e >= N_EDGES) return;
    int pos = atomicAdd(&cursor[dst[e]], 1);
    ssrc[pos] = src[e];
    sw[pos] = w[e];
}

// ===========================================================================
// CSR gather-aggregate, 4x unrolled edge loop
// ===========================================================================
template<int F, bool FUSED>
__global__ void gather_kernel(const int* __restrict__ rowptr, const int* __restrict__ ssrc,
                              const float* __restrict__ sw, const float* __restrict__ y,
                              const float* __restrict__ r, const float* __restrict__ b,
                              float* __restrict__ out) {
    constexpr int G = F / 4;
    constexpr int NPB = 256 / G;
    const int tid = threadIdx.x;
    const int c = tid % G;
    const int ln = tid / G;
    const int n = blockIdx.x * NPB + ln;
    if (n >= N_NODES) return;
    const int beg = rowptr[n], end = rowptr[n + 1];
    float4 acc = {0.f, 0.f, 0.f, 0.f};
    int i = beg;
    for (; i + 3 < end; i += 4) {
        int s0 = ssrc[i], s1 = ssrc[i + 1], s2 = ssrc[i + 2], s3 = ssrc[i + 3];
        float w0 = sw[i], w1 = sw[i + 1], w2 = sw[i + 2], w3 = sw[i + 3];
        float4 v0 = *(reinterpret_cast<const float4*>(y + (size_t)s0 * F) + c);
        float4 v1 = *(reinterpret_cast<const float4*>(y + (size_t)s1 * F) + c);
        float4 v2 = *(reinterpret_cast<const float4*>(y + (size_t)s2 * F) + c);
        float4 v3 = *(reinterpret_cast<const float4*>(y + (size_t)s3 * F) + c);
        acc.x += v0.x * w0 + v1.x * w1 + v2.x * w2 + v3.x * w3;
        acc.y += v0.y * w0 + v1.y * w1 + v2.y * w2 + v3.y * w3;
        acc.z += v0.z * w0 + v1.z * w1 + v2.z * w2 + v3.z * w3;
        acc.w += v0.w * w0 + v1.w * w1 + v2.w * w2 + v3.w * w3;
    }
    for (; i < end; ++i) {
        int s0 = ssrc[i];
        float w0 = sw[i];
        float4 v0 = *(reinterpret_cast<const float4*>(y + (size_t)s0 * F) + c);
        acc.x += v0.x * w0; acc.y += v0.y * w0; acc.z += v0.z * w0; acc.w += v0.w * w0;
    }
    if constexpr (FUSED) {
        float4 rv = *(reinterpret_cast<const float4*>(r + (size_t)n * F) + c);
        float4 bv = *(reinterpret_cast<const float4*>(b) + c);
        acc.x = fmaxf(acc.x + rv.x + bv.x, 0.f);
        acc.y = fmaxf(acc.y + rv.y + bv.y, 0.f);
        acc.z = fmaxf(acc.z + rv.z + bv.z, 0.f);
        acc.w = fmaxf(acc.w + rv.w + bv.w, 0.f);
    }
    *(reinterpret_cast<float4*>(out + (size_t)n * F) + c) = acc;
}

__global__ void gather5_kernel(const int* __restrict__ rowptr, const int* __restrict__ ssrc,
                               const float* __restrict__ sw, const float* __restrict__ x,
                               float* __restrict__ agg) {
    int n = blockIdx.x * blockDim.x + threadIdx.x;
    if (n >= N_NODES) return;
    float a0 = 0.f, a1 = 0.f, a2 = 0.f, a3 = 0.f, a4 = 0.f;
    for (int i = rowptr[n]; i < rowptr[n + 1]; ++i) {
        int s = ssrc[i];
        float we = sw[i];
        const float* xs = x + (size_t)s * 5;
        a0 += xs[0] * we; a1 += xs[1] * we; a2 += xs[2] * we;
        a3 += xs[3] * we; a4 += xs[4] * we;
    }
    float* o = agg + (size_t)n * 5;
    o[0] = a0; o[1] = a1; o[2] = a2; o[3] = a3; o[4] = a4;
}

// ===========================================================================
// Pipelined LDS-tiled GEMM, 4 nodes x 8 cols per thread (halves LDS-pipe
// demand vs 8x4), fully-unrolled k-loop (weight addresses fold to immediates).
//  DUAL=false (conv): out1 = relu([in1|in2] @ [Wrel;Wroot] + brel)  (K = 2*FIN)
//  DUAL=true:         out1 = in1@Wrel ; out2 = in1@Wroot            (K = FIN)
// ===========================================================================
template<int FIN, int FOUT, bool DUAL>
__global__ __launch_bounds__(256, 3)
void gemm_kernel(const float* __restrict__ in1, const float* __restrict__ in2,
                 const float* __restrict__ Wrel, const float* __restrict__ Wroot,
                 const float* __restrict__ brel,
                 float* __restrict__ out1, float* __restrict__ out2) {
    constexpr int KT = DUAL ? FIN : 2 * FIN;            // total K
    constexpr int JG = DUAL ? (FOUT / 4) : (FOUT / 8);  // 8-col groups (dual: both mats)
    constexpr int NG = 256 / JG;
    constexpr int TN = NG * 4;                          // nodes per block
    constexpr int CH = KT / 4;                          // float4 chunks per row
    constexpr int C1 = FIN / 4;                         // chunks from in1
    constexpr int TOT = TN * CH;                        // 2048 for all four shapes

    __shared__ float smem[TN * KT];                     // 32 KB

    const int tid = threadIdx.x;
    const int n0 = blockIdx.x * TN;
    const bool full = (n0 + TN <= N_NODES);

    // ---- stage tile (rows: [in1 | in2] for conv)
    #pragma unroll
    for (int r2 = 0; r2 < TOT / 256; ++r2) {
        int idx = r2 * 256 + tid;
        int n = idx / CH, c = idx - n * CH;
        int gn = n0 + n;
        float4 v = {0.f, 0.f, 0.f, 0.f};
        if (full || gn < N_NODES) {
            if constexpr (DUAL) {
                v = *(const float4*)(in1 + (size_t)gn * FIN + c * 4);
            } else {
                v = (c < C1) ? *(const float4*)(in1 + (size_t)gn * FIN + c * 4)
                             : *(const float4*)(in2 + (size_t)gn * FIN + (c - C1) * 4);
            }
        }
        *(float4*)(smem + n * KT + c * 4) = v;
    }
    __syncthreads();

    const int jg = tid % JG;
    const int ng = tid / JG;
    const float* sA = smem + (ng * 4) * KT;

    const float* pW1;       // weight base for k < FIN
    const float* pW2;       // base for k >= FIN, pre-shifted so +k*FOUT works
    float* outd = out1;
    int col;
    if constexpr (DUAL) {
        const bool second = jg >= (FOUT / 8);
        pW1 = second ? Wroot : Wrel;
        pW2 = pW1;
        outd = second ? out2 : out1;
        col = (second ? jg - FOUT / 8 : jg) * 8;
    } else {
        pW1 = Wrel;
        pW2 = Wroot - (ptrdiff_t)FIN * FOUT;   // pW2 + k*FOUT == Wroot + (k-FIN)*FOUT
        col = jg * 8;
    }

    float acc[4][8] = {};
    float4 aA[4], aB[4], wA[8], wB[8];

#define LOADT(A_, W_, K0)                                                     \
    { _Pragma("unroll") for (int i = 0; i < 4; ++i)                           \
          A_[i] = *(const float4*)(sA + i * KT + (K0));                       \
      _Pragma("unroll") for (int kk = 0; kk < 4; ++kk) {                      \
          const float* base_ = (DUAL || ((K0) + kk) < FIN) ? pW1 : pW2;       \
          W_[kk * 2]     = *(const float4*)(base_ + (ptrdiff_t)((K0) + kk) * FOUT + col);     \
          W_[kk * 2 + 1] = *(const float4*)(base_ + (ptrdiff_t)((K0) + kk) * FOUT + col + 4); } }

#define FMAT(A_, W_)                                                          \
    { _Pragma("unroll") for (int i = 0; i < 4; ++i) {                         \
        float a0_ = A_[i].x, a1_ = A_[i].y, a2_ = A_[i].z, a3_ = A_[i].w;     \
        acc[i][0] += a0_ * W_[0].x; acc[i][1] += a0_ * W_[0].y;               \
        acc[i][2] += a0_ * W_[0].z; acc[i][3] += a0_ * W_[0].w;               \
        acc[i][4] += a0_ * W_[1].x; acc[i][5] += a0_ * W_[1].y;               \
        acc[i][6] += a0_ * W_[1].z; acc[i][7] += a0_ * W_[1].w;               \
        acc[i][0] += a1_ * W_[2].x; acc[i][1] += a1_ * W_[2].y;               \
        acc[i][2] += a1_ * W_[2].z; acc[i][3] += a1_ * W_[2].w;               \
        acc[i][4] += a1_ * W_[3].x; acc[i][5] += a1_ * W_[3].y;               \
        acc[i][6] += a1_ * W_[3].z; acc[i][7] += a1_ * W_[3].w;               \
        acc[i][0] += a2_ * W_[4].x; acc[i][1] += a2_ * W_[4].y;               \
        acc[i][2] += a2_ * W_[4].z; acc[i][3] += a2_ * W_[4].w;               \
        acc[i][4] += a2_ * W_[5].x; acc[i][5] += a2_ * W_[5].y;               \
        acc[i][6] += a2_ * W_[5].z; acc[i][7] += a2_ * W_[5].w;               \
        acc[i][0] += a3_ * W_[6].x; acc[i][1] += a3_ * W_[6].y;               \
        acc[i][2] += a3_ * W_[6].z; acc[i][3] += a3_ * W_[6].w;               \
        acc[i][4] += a3_ * W_[7].x; acc[i][5] += a3_ * W_[7].y;               \
        acc[i][6] += a3_ * W_[7].z; acc[i][7] += a3_ * W_[7].w; } }

    // prologue: groups 0 and 4 in flight
    LOADT(aA, wA, 0);
    LOADT(aB, wB, 4);
    // fully-unrolled steady state: K0 literal -> weight addresses fold
    #pragma unroll
    for (int k0 = 0; k0 < KT - 8; k0 += 8) {
        FMAT(aA, wA);
        LOADT(aA, wA, k0 + 8);
        FMAT(aB, wB);
        LOADT(aB, wB, k0 + 12);
    }
    FMAT(aA, wA);
    FMAT(aB, wB);

#undef LOADT
#undef FMAT

    // ---- write (two float4 per row)
    if constexpr (DUAL) {
        #pragma unroll
        for (int i = 0; i < 4; ++i) {
            int n = n0 + ng * 4 + i;
            if (full || n < N_NODES) {
                float4 o0 = {acc[i][0], acc[i][1], acc[i][2], acc[i][3]};
                float4 o1 = {acc[i][4], acc[i][5], acc[i][6], acc[i][7]};
                *(float4*)(outd + (size_t)n * FOUT + col) = o0;
                *(float4*)(outd + (size_t)n * FOUT + col + 4) = o1;
            }
        }
    } else {
        float4 b0 = *(const float4*)(brel + col);
        float4 b1 = *(const float4*)(brel + col + 4);
        #pragma unroll
        for (int i = 0; i < 4; ++i) {
            int n = n0 + ng * 4 + i;
            if (full || n < N_NODES) {
                float4 o0 = {fmaxf(acc[i][0] + b0.x, 0.f), fmaxf(acc[i][1] + b0.y, 0.f),
                             fmaxf(acc[i][2] + b0.z, 0.f), fmaxf(acc[i][3] + b0.w, 0.f)};
                float4 o1 = {fmaxf(acc[i][4] + b1.x, 0.f), fmaxf(acc[i][5] + b1.y, 0.f),
                             fmaxf(acc[i][6] + b1.z, 0.f), fmaxf(acc[i][7] + b1.w, 0.f)};
                *(float4*)(out1 + (size_t)n * FOUT + col) = o0;
                *(float4*)(out1 + (size_t)n * FOUT + col + 4) = o1;
            }
        }
    }
}

// ===========================================================================
// Layer-0 conv (FIN=5): simple register-tiled version
// ===========================================================================
template<int FIN, int FOUT>
__global__ void conv_out_kernel(const float* __restrict__ agg, const float* __restrict__ x,
                                const float* __restrict__ Wrel, const float* __restrict__ brel,
                                const float* __restrict__ Wroot, float* __restrict__ out) {
    constexpr int JG = FOUT / 4;
    constexpr int NG = 256 / JG;
    constexpr int NT = NG * 4;
    const int tid = threadIdx.x;
    const int jg = tid % JG;
    const int ng = tid / JG;
    const int n0 = blockIdx.x * NT + ng * 4;

    float acc[4][4] = {};
    for (int k = 0; k < FIN; ++k) {
        float a[4], xx[4];
        #pragma unroll
        for (int i = 0; i < 4; ++i) {
            int n = n0 + i;
            a[i]  = (n < N_NODES) ? agg[(size_t)n * FIN + k] : 0.f;
            xx[i] = (n < N_NODES) ? x[(size_t)n * FIN + k]   : 0.f;
        }
        float4 wr = *reinterpret_cast<const float4*>(Wrel  + (size_t)k * FOUT + jg * 4);
        float4 wo = *reinterpret_cast<const float4*>(Wroot + (size_t)k * FOUT + jg * 4);
        float wrv[4] = {wr.x, wr.y, wr.z, wr.w};
        float wov[4] = {wo.x, wo.y, wo.z, wo.w};
        #pragma unroll
        for (int i = 0; i < 4; ++i)
            #pragma unroll
            for (int j = 0; j < 4; ++j)
                acc[i][j] += a[i] * wrv[j] + xx[i] * wov[j];
    }
    float4 b4 = *reinterpret_cast<const float4*>(brel + jg * 4);
    float bv[4] = {b4.x, b4.y, b4.z, b4.w};
    #pragma unroll
    for (int i = 0; i < 4; ++i) {
        int n = n0 + i;
        if (n < N_NODES) {
            #pragma unroll
            for (int j = 0; j < 4; ++j)
                out[(size_t)n * FOUT + jg * 4 + j] = fmaxf(acc[i][j] + bv[j], 0.f);
        }
    }
}

// ===========================================================================
// Fused mean-pool + MLP head (batch sorted -> contiguous ranges, no atomics)
// ===========================================================================
__global__ void pool_mlp_kernel(const float* __restrict__ x, const int* __restrict__ batch,
                                const float* __restrict__ W0, const float* __restrict__ b0,
                                const float* __restrict__ W1, const float* __restrict__ b1,
                                const float* __restrict__ W2, const float* __restrict__ b2,
                                float* __restrict__ out) {
    const int g = blockIdx.x;
    auto lb = [&](int key) {
        int lo = 0, hi = N_NODES;
        while (lo < hi) {
            int mid = (lo + hi) >> 1;
            if (batch[mid] < key) lo = mid + 1; else hi = mid;
        }
        return lo;
    };
    const int beg = lb(g), end = lb(g + 1);

    const int t = threadIdx.x;
    const int q = t & 7;
    const int r = t >> 3;

    float4 s = {0.f, 0.f, 0.f, 0.f};
    for (int n = beg + r; n < end; n += 32) {
        float4 v = *(reinterpret_cast<const float4*>(x + (size_t)n * 32) + q);
        s.x += v.x; s.y += v.y; s.z += v.z; s.w += v.w;
    }
    __shared__ float4 red[32][8];
    red[r][q] = s;
    __syncthreads();

    __shared__ float h0[32], h1[32], h2[16];
    if (r == 0) {
        float4 tot = {0.f, 0.f, 0.f, 0.f};
        #pragma unroll
        for (int i = 0; i < 32; ++i) {
            float4 v = red[i][q];
            tot.x += v.x; tot.y += v.y; tot.z += v.z; tot.w += v.w;
        }
        float c = fmaxf((float)(end - beg), 1.0f);
        h0[q * 4 + 0] = tot.x / c;
        h0[q * 4 + 1] = tot.y / c;
        h0[q * 4 + 2] = tot.z / c;
        h0[q * 4 + 3] = tot.w / c;
    }
    __syncthreads();
    if (t < 32) {
        float s1 = b0[t];
        for (int k = 0; k < 32; ++k) s1 += h0[k] * W0[k * 32 + t];
        h1[t] = fmaxf(s1, 0.f);
    }
    __syncthreads();
    if (t < 16) {
        float s2 = b1[t];
        for (int k = 0; k < 32; ++k) s2 += h1[k] * W1[k * 16 + t];
        h2[t] = fmaxf(s2, 0.f);
    }
    __syncthreads();
    if (t == 0) {
        float s3 = b2[0];
        for (int k = 0; k < 16; ++k) s3 += h2[k] * W2[k];
        out[g] = s3;
    }
}

// ===========================================================================
extern "C" void kernel_launch(void* const* d_in, const int* in_sizes, int n_in,
                              void* d_out, int out_size, void* d_ws, size_t ws_size,
                              hipStream_t stream) {
    const float* x_in  = (const float*)d_in[0];
    const int*   ei    = (const int*)d_in[1];
    const int*   src   = ei;
    const int*   dst   = ei + N_EDGES;
    const float* ew    = (const float*)d_in[2];
    const int*   batch = (const int*)d_in[3];

    const float* Wrel[5]  = {(const float*)d_in[4],  (const float*)d_in[7],  (const float*)d_in[10],
                             (const float*)d_in[13], (const float*)d_in[16]};
    const float* brel[5]  = {(const float*)d_in[5],  (const float*)d_in[8],  (const float*)d_in[11],
                             (const float*)d_in[14], (const float*)d_in[17]};
    const float* Wroot[5] = {(const float*)d_in[6],  (const float*)d_in[9],  (const float*)d_in[12],
                             (const float*)d_in[15], (const float*)d_in[18]};
    const float* mW0 = (const float*)d_in[19];
    const float* mb0 = (const float*)d_in[20];
    const float* mW1 = (const float*)d_in[21];
    const float* mb1 = (const float*)d_in[22];
    const float* mW2 = (const float*)d_in[23];
    const float* mb2 = (const float*)d_in[24];

    float* ws = (float*)d_ws;
    float* A = ws;                                 // [N,64]
    float* B = A + (size_t)N_NODES * 64;           // [N,128]
    float* C = B + (size_t)N_NODES * 128;          // [N,64]
    int*   rowptr = (int*)(C + (size_t)N_NODES * 64);   // N+1
    int*   cursor = rowptr + (N_NODES + 2);             // N
    int*   deg    = cursor + N_NODES;                   // N
    int*   bsum   = deg + N_NODES;                      // SCAN_NB
    int*   ssrc   = bsum + 128;                         // E
    float* sw     = (float*)(ssrc + N_EDGES);           // E

    const int BS = 256;
    auto blocks = [](long long total, int bs) { return (int)((total + bs - 1) / bs); };

    // ---- CSR build
    hipMemsetAsync(deg, 0, N_NODES * sizeof(int), stream);
    hist_kernel<<<blocks(N_EDGES, BS), BS, 0, stream>>>(dst, deg);
    scan_p1_kernel<<<SCAN_NB, SCAN_BS, 0, stream>>>(deg, bsum);
    scan_p2_kernel<<<1, 128, 0, stream>>>(bsum, rowptr);
    scan_p3_kernel<<<SCAN_NB, SCAN_BS, 0, stream>>>(deg, bsum, rowptr, cursor);
    fill_kernel<<<blocks(N_EDGES, BS), BS, 0, stream>>>(src, dst, ew, cursor, ssrc, sw);

    const int G64  = (N_NODES + 63) / 64;    // TN=64 grids
    const int G128 = (N_NODES + 127) / 128;  // TN=128 grids

    // ---- Layer 0: 5 -> 32.  gather(x_in) -> C, conv -> B[N,32]
    gather5_kernel<<<blocks(N_NODES, BS), BS, 0, stream>>>(rowptr, ssrc, sw, x_in, C);
    conv_out_kernel<5, 32><<<blocks(N_NODES, 128), BS, 0, stream>>>(C, x_in, Wrel[0], brel[0], Wroot[0], B);

    // ---- Layer 1: 32 -> 64.  gather(B,w32) -> C, GEMM -> A[N,64]   (TN=128)
    gather_kernel<32, false><<<blocks(N_NODES, 32), BS, 0, stream>>>(rowptr, ssrc, sw, B, nullptr, nullptr, C);
    gemm_kernel<32, 64, false><<<G128, 256, 0, stream>>>(C, B, Wrel[1], Wroot[1], brel[1], A, nullptr);

    // ---- Layer 2: 64 -> 128. gather(A,w64) -> C, GEMM -> B[N,128]  (TN=64)
    gather_kernel<64, false><<<blocks(N_NODES, 16), BS, 0, stream>>>(rowptr, ssrc, sw, A, nullptr, nullptr, C);
    gemm_kernel<64, 128, false><<<G64, 256, 0, stream>>>(C, A, Wrel[2], Wroot[2], brel[2], B, nullptr);

    // ---- Layer 3: 128 -> 64. dual GEMM: y=C, r=A; fused gather -> B[N,64]  (TN=64)
    gemm_kernel<128, 64, true><<<G64, 256, 0, stream>>>(B, nullptr, Wrel[3], Wroot[3], nullptr, C, A);
    gather_kernel<64, true><<<blocks(N_NODES, 16), BS, 0, stream>>>(rowptr, ssrc, sw, C, A, brel[3], B);

    // ---- Layer 4: 64 -> 32.  dual GEMM: y=C, r=A; fused gather -> B[N,32]  (TN=128)
    gemm_kernel<64, 32, true><<<G128, 256, 0, stream>>>(B, nullptr, Wrel[4], Wroot[4], nullptr, C, A);
    gather_kernel<32, true><<<blocks(N_NODES, 32), BS, 0, stream>>>(rowptr, ssrc, sw, C, A, brel[4], B);

    // ---- Fused mean pool + MLP
    pool_mlp_kernel<<<NUM_GRAPHS, 256, 0, stream>>>(B, batch, mW0, mb0, mW1, mb1, mW2, mb2, (float*)d_out);
}

// Round 9
// 682.651 us; speedup vs baseline: 8.4874x; 8.4874x over previous
//
#include <hip/hip_runtime.h>

#define N_NODES 100000
#define N_EDGES 600000
#define NUM_GRAPHS 256

#define SCAN_BS   256
#define SCAN_CH   4
#define SCAN_CHUNK (SCAN_BS * SCAN_CH)                      // 1024
#define SCAN_NB   ((N_NODES + SCAN_CHUNK - 1) / SCAN_CHUNK) // 98

// ===========================================================================
// CSR build: histogram -> 3-phase scan -> fill (once per launch, reused 5x)
// ===========================================================================
__global__ void hist_kernel(const int* __restrict__ dst, int* __restrict__ deg) {
    int e = blockIdx.x * blockDim.x + threadIdx.x;
    if (e < N_EDGES) atomicAdd(&deg[dst[e]], 1);
}

__global__ void scan_p1_kernel(const int* __restrict__ deg, int* __restrict__ bsum) {
    __shared__ int sh[SCAN_BS];
    const int b = blockIdx.x, t = threadIdx.x;
    const int base = b * SCAN_CHUNK + t * SCAN_CH;
    int s = 0;
    #pragma unroll
    for (int k = 0; k < SCAN_CH; ++k) {
        int i = base + k;
        if (i < N_NODES) s += deg[i];
    }
    sh[t] = s;
    __syncthreads();
    for (int off = SCAN_BS / 2; off > 0; off >>= 1) {
        if (t < off) sh[t] += sh[t + off];
        __syncthreads();
    }
    if (t == 0) bsum[b] = sh[0];
}

__global__ void scan_p2_kernel(int* __restrict__ bsum, int* __restrict__ rowptr) {
    __shared__ int sh[128];
    const int t = threadIdx.x;
    int v = (t < SCAN_NB) ? bsum[t] : 0;
    sh[t] = v;
    __syncthreads();
    for (int off = 1; off < 128; off <<= 1) {
        int u = (t >= off) ? sh[t - off] : 0;
        __syncthreads();
        sh[t] += u;
        __syncthreads();
    }
    if (t < SCAN_NB) bsum[t] = sh[t] - v;
    if (t == 0) rowptr[N_NODES] = N_EDGES;
}

__global__ void scan_p3_kernel(const int* __restrict__ deg, const int* __restrict__ bsum,
                               int* __restrict__ rowptr, int* __restrict__ cursor) {
    __shared__ int sh[SCAN_BS];
    const int b = blockIdx.x, t = threadIdx.x;
    const int base = b * SCAN_CHUNK + t * SCAN_CH;
    int v[SCAN_CH];
    int s = 0;
    #pragma unroll
    for (int k = 0; k < SCAN_CH; ++k) {
        int i = base + k;
        v[k] = (i < N_NODES) ? deg[i] : 0;
        s += v[k];
    }
    sh[t] = s;
    __syncthreads();
    for (int off = 1; off < SCAN_BS; off <<= 1) {
        int u = (t >= off) ? sh[t - off] : 0;
        __syncthreads();
        sh[t] += u;
        __syncthreads();
    }
    int run = bsum[b] + sh[t] - s;
    #pragma unroll
    for (int k = 0; k < SCAN_CH; ++k) {
        int i = base + k;
        if (i < N_NODES) { rowptr[i] = run; cursor[i] = run; }
        run += v[k];
    }
}

__global__ void fill_kernel(const int* __restrict__ src, const int* __restrict__ dst,
                            const float* __restrict__ w, int* __restrict__ cursor,
                            int* __restrict__ ssrc, float* __restrict__ sw) {
    int e = blockIdx.x * blockDim.x + threadIdx.x;
    if (e >= N_EDGES) return;
    int pos = atomicAdd(&cursor[dst[e]], 1);
    ssrc[pos] = src[e];
    sw[pos] = w[e];
}

// ===========================================================================
// CSR gather-aggregate, 4x unrolled edge loop
// ===========================================================================
template<int F, bool FUSED>
__global__ void gather_kernel(const int* __restrict__ rowptr, const int* __restrict__ ssrc,
                              const float* __restrict__ sw, const float* __restrict__ y,
                              const float* __restrict__ r, const float* __restrict__ b,
                              float* __restrict__ out) {
    constexpr int G = F / 4;
    constexpr int NPB = 256 / G;
    const int tid = threadIdx.x;
    const int c = tid % G;
    const int ln = tid / G;
    const int n = blockIdx.x * NPB + ln;
    if (n >= N_NODES) return;
    const int beg = rowptr[n], end = rowptr[n + 1];
    float4 acc = {0.f, 0.f, 0.f, 0.f};
    int i = beg;
    for (; i + 3 < end; i += 4) {
        int s0 = ssrc[i], s1 = ssrc[i + 1], s2 = ssrc[i + 2], s3 = ssrc[i + 3];
        float w0 = sw[i], w1 = sw[i + 1], w2 = sw[i + 2], w3 = sw[i + 3];
        float4 v0 = *(reinterpret_cast<const float4*>(y + (size_t)s0 * F) + c);
        float4 v1 = *(reinterpret_cast<const float4*>(y + (size_t)s1 * F) + c);
        float4 v2 = *(reinterpret_cast<const float4*>(y + (size_t)s2 * F) + c);
        float4 v3 = *(reinterpret_cast<const float4*>(y + (size_t)s3 * F) + c);
        acc.x += v0.x * w0 + v1.x * w1 + v2.x * w2 + v3.x * w3;
        acc.y += v0.y * w0 + v1.y * w1 + v2.y * w2 + v3.y * w3;
        acc.z += v0.z * w0 + v1.z * w1 + v2.z * w2 + v3.z * w3;
        acc.w += v0.w * w0 + v1.w * w1 + v2.w * w2 + v3.w * w3;
    }
    for (; i < end; ++i) {
        int s0 = ssrc[i];
        float w0 = sw[i];
        float4 v0 = *(reinterpret_cast<const float4*>(y + (size_t)s0 * F) + c);
        acc.x += v0.x * w0; acc.y += v0.y * w0; acc.z += v0.z * w0; acc.w += v0.w * w0;
    }
    if constexpr (FUSED) {
        float4 rv = *(reinterpret_cast<const float4*>(r + (size_t)n * F) + c);
        float4 bv = *(reinterpret_cast<const float4*>(b) + c);
        acc.x = fmaxf(acc.x + rv.x + bv.x, 0.f);
        acc.y = fmaxf(acc.y + rv.y + bv.y, 0.f);
        acc.z = fmaxf(acc.z + rv.z + bv.z, 0.f);
        acc.w = fmaxf(acc.w + rv.w + bv.w, 0.f);
    }
    *(reinterpret_cast<float4*>(out + (size_t)n * F) + c) = acc;
}

__global__ void gather5_kernel(const int* __restrict__ rowptr, const int* __restrict__ ssrc,
                               const float* __restrict__ sw, const float* __restrict__ x,
                               float* __restrict__ agg) {
    int n = blockIdx.x * blockDim.x + threadIdx.x;
    if (n >= N_NODES) return;
    float a0 = 0.f, a1 = 0.f, a2 = 0.f, a3 = 0.f, a4 = 0.f;
    for (int i = rowptr[n]; i < rowptr[n + 1]; ++i) {
        int s = ssrc[i];
        float we = sw[i];
        const float* xs = x + (size_t)s * 5;
        a0 += xs[0] * we; a1 += xs[1] * we; a2 += xs[2] * we;
        a3 += xs[3] * we; a4 += xs[4] * we;
    }
    float* o = agg + (size_t)n * 5;
    o[0] = a0; o[1] = a1; o[2] = a2; o[3] = a3; o[4] = a4;
}

// ===========================================================================
// Pipelined LDS-tiled GEMM: 4 nodes x 8 cols per thread (halves LDS-pipe
// demand vs 8x4), runtime-k0 ping-pong loop (R7's proven no-spill schedule),
// padded LDS rows (KP = KT+4) so the 4 ng-groups/wave hit alternating banks.
//  DUAL=false (conv): out1 = relu([in1|in2] @ [Wrel;Wroot] + brel)  (K = 2*FIN)
//  DUAL=true:         out1 = in1@Wrel ; out2 = in1@Wroot            (K = FIN)
// ===========================================================================
template<int FIN, int FOUT, bool DUAL>
__global__ __launch_bounds__(256, 3)
void gemm_kernel(const float* __restrict__ in1, const float* __restrict__ in2,
                 const float* __restrict__ Wrel, const float* __restrict__ Wroot,
                 const float* __restrict__ brel,
                 float* __restrict__ out1, float* __restrict__ out2) {
    constexpr int KT = DUAL ? FIN : 2 * FIN;            // total K
    constexpr int KP = KT + 4;                          // padded LDS row
    constexpr int JG = DUAL ? (FOUT / 4) : (FOUT / 8);  // 8-col groups (dual: both mats)
    constexpr int NG = 256 / JG;
    constexpr int TN = NG * 4;                          // nodes per block
    constexpr int CH = KT / 4;                          // float4 chunks per row
    constexpr int TOT = TN * CH;                        // 2048 for all four shapes

    __shared__ float smem[TN * KP];                     // <= 34 KB

    const int tid = threadIdx.x;
    const int n0 = blockIdx.x * TN;
    const bool full = (n0 + TN <= N_NODES);
    constexpr int C1 = FIN / 4;                         // chunks from in1

    // ---- stage tile (rows: [in1 | in2] for conv)
    #pragma unroll
    for (int r2 = 0; r2 < TOT / 256; ++r2) {
        int idx = r2 * 256 + tid;
        int n = idx / CH, c = idx - n * CH;
        int gn = n0 + n;
        float4 v = {0.f, 0.f, 0.f, 0.f};
        if (full || gn < N_NODES) {
            if constexpr (DUAL) {
                v = *(const float4*)(in1 + (size_t)gn * FIN + c * 4);
            } else {
                v = (c < C1) ? *(const float4*)(in1 + (size_t)gn * FIN + c * 4)
                             : *(const float4*)(in2 + (size_t)gn * FIN + (c - C1) * 4);
            }
        }
        *(float4*)(smem + n * KP + c * 4) = v;
    }
    __syncthreads();

    const int jg = tid % JG;
    const int ng = tid / JG;
    const float* sA = smem + (ng * 4) * KP;

    const float* pW1;       // weight base for k < FIN
    const float* pW2;       // base for k >= FIN, pre-shifted so +k*FOUT works
    float* outd = out1;
    int col;
    if constexpr (DUAL) {
        const bool second = jg >= (FOUT / 8);
        pW1 = second ? Wroot : Wrel;
        pW2 = pW1;
        outd = second ? out2 : out1;
        col = (second ? jg - FOUT / 8 : jg) * 8;
    } else {
        pW1 = Wrel;
        pW2 = Wroot - (ptrdiff_t)FIN * FOUT;   // pW2 + k*FOUT == Wroot + (k-FIN)*FOUT
        col = jg * 8;
    }

    float acc[4][8] = {};
    float4 aA[4], aB[4], wA[8], wB[8];

#define LOADT(A_, W_, K0)                                                     \
    { _Pragma("unroll") for (int i = 0; i < 4; ++i)                           \
          A_[i] = *(const float4*)(sA + i * KP + (K0));                       \
      _Pragma("unroll") for (int kk = 0; kk < 4; ++kk) {                      \
          const float* base_ = (DUAL || ((K0) + kk) < FIN) ? pW1 : pW2;       \
          W_[kk * 2]     = *(const float4*)(base_ + (ptrdiff_t)((K0) + kk) * FOUT + col);     \
          W_[kk * 2 + 1] = *(const float4*)(base_ + (ptrdiff_t)((K0) + kk) * FOUT + col + 4); } }

#define FMAT(A_, W_)                                                          \
    { _Pragma("unroll") for (int i = 0; i < 4; ++i) {                         \
        float a0_ = A_[i].x, a1_ = A_[i].y, a2_ = A_[i].z, a3_ = A_[i].w;     \
        acc[i][0] += a0_ * W_[0].x; acc[i][1] += a0_ * W_[0].y;               \
        acc[i][2] += a0_ * W_[0].z; acc[i][3] += a0_ * W_[0].w;               \
        acc[i][4] += a0_ * W_[1].x; acc[i][5] += a0_ * W_[1].y;               \
        acc[i][6] += a0_ * W_[1].z; acc[i][7] += a0_ * W_[1].w;               \
        acc[i][0] += a1_ * W_[2].x; acc[i][1] += a1_ * W_[2].y;               \
        acc[i][2] += a1_ * W_[2].z; acc[i][3] += a1_ * W_[2].w;               \
        acc[i][4] += a1_ * W_[3].x; acc[i][5] += a1_ * W_[3].y;               \
        acc[i][6] += a1_ * W_[3].z; acc[i][7] += a1_ * W_[3].w;               \
        acc[i][0] += a2_ * W_[4].x; acc[i][1] += a2_ * W_[4].y;               \
        acc[i][2] += a2_ * W_[4].z; acc[i][3] += a2_ * W_[4].w;               \
        acc[i][4] += a2_ * W_[5].x; acc[i][5] += a2_ * W_[5].y;               \
        acc[i][6] += a2_ * W_[5].z; acc[i][7] += a2_ * W_[5].w;               \
        acc[i][0] += a3_ * W_[6].x; acc[i][1] += a3_ * W_[6].y;               \
        acc[i][2] += a3_ * W_[6].z; acc[i][3] += a3_ * W_[6].w;               \
        acc[i][4] += a3_ * W_[7].x; acc[i][5] += a3_ * W_[7].y;               \
        acc[i][6] += a3_ * W_[7].z; acc[i][7] += a3_ * W_[7].w; } }

    // prologue: groups 0 and 4 in flight
    LOADT(aA, wA, 0);
    LOADT(aB, wB, 4);
    // steady state (runtime k0, no full unroll -> no spill): compute k0,k0+4
    // while prefetching k0+8,k0+12
    #pragma unroll 1
    for (int k0 = 0; k0 < KT - 8; k0 += 8) {
        FMAT(aA, wA);
        LOADT(aA, wA, k0 + 8);
        FMAT(aB, wB);
        LOADT(aB, wB, k0 + 12);
    }
    FMAT(aA, wA);
    FMAT(aB, wB);

#undef LOADT
#undef FMAT

    // ---- write (two float4 per row)
    if constexpr (DUAL) {
        #pragma unroll
        for (int i = 0; i < 4; ++i) {
            int n = n0 + ng * 4 + i;
            if (full || n < N_NODES) {
                float4 o0 = {acc[i][0], acc[i][1], acc[i][2], acc[i][3]};
                float4 o1 = {acc[i][4], acc[i][5], acc[i][6], acc[i][7]};
                *(float4*)(outd + (size_t)n * FOUT + col) = o0;
                *(float4*)(outd + (size_t)n * FOUT + col + 4) = o1;
            }
        }
    } else {
        float4 b0 = *(const float4*)(brel + col);
        float4 b1 = *(const float4*)(brel + col + 4);
        #pragma unroll
        for (int i = 0; i < 4; ++i) {
            int n = n0 + ng * 4 + i;
            if (full || n < N_NODES) {
                float4 o0 = {fmaxf(acc[i][0] + b0.x, 0.f), fmaxf(acc[i][1] + b0.y, 0.f),
                             fmaxf(acc[i][2] + b0.z, 0.f), fmaxf(acc[i][3] + b0.w, 0.f)};
                float4 o1 = {fmaxf(acc[i][4] + b1.x, 0.f), fmaxf(acc[i][5] + b1.y, 0.f),
                             fmaxf(acc[i][6] + b1.z, 0.f), fmaxf(acc[i][7] + b1.w, 0.f)};
                *(float4*)(out1 + (size_t)n * FOUT + col) = o0;
                *(float4*)(out1 + (size_t)n * FOUT + col + 4) = o1;
            }
        }
    }
}

// ===========================================================================
// Layer-0 conv (FIN=5): simple register-tiled version
// ===========================================================================
template<int FIN, int FOUT>
__global__ void conv_out_kernel(const float* __restrict__ agg, const float* __restrict__ x,
                                const float* __restrict__ Wrel, const float* __restrict__ brel,
                                const float* __restrict__ Wroot, float* __restrict__ out) {
    constexpr int JG = FOUT / 4;
    constexpr int NG = 256 / JG;
    constexpr int NT = NG * 4;
    const int tid = threadIdx.x;
    const int jg = tid % JG;
    const int ng = tid / JG;
    const int n0 = blockIdx.x * NT + ng * 4;

    float acc[4][4] = {};
    for (int k = 0; k < FIN; ++k) {
        float a[4], xx[4];
        #pragma unroll
        for (int i = 0; i < 4; ++i) {
            int n = n0 + i;
            a[i]  = (n < N_NODES) ? agg[(size_t)n * FIN + k] : 0.f;
            xx[i] = (n < N_NODES) ? x[(size_t)n * FIN + k]   : 0.f;
        }
        float4 wr = *reinterpret_cast<const float4*>(Wrel  + (size_t)k * FOUT + jg * 4);
        float4 wo = *reinterpret_cast<const float4*>(Wroot + (size_t)k * FOUT + jg * 4);
        float wrv[4] = {wr.x, wr.y, wr.z, wr.w};
        float wov[4] = {wo.x, wo.y, wo.z, wo.w};
        #pragma unroll
        for (int i = 0; i < 4; ++i)
            #pragma unroll
            for (int j = 0; j < 4; ++j)
                acc[i][j] += a[i] * wrv[j] + xx[i] * wov[j];
    }
    float4 b4 = *reinterpret_cast<const float4*>(brel + jg * 4);
    float bv[4] = {b4.x, b4.y, b4.z, b4.w};
    #pragma unroll
    for (int i = 0; i < 4; ++i) {
        int n = n0 + i;
        if (n < N_NODES) {
            #pragma unroll
            for (int j = 0; j < 4; ++j)
                out[(size_t)n * FOUT + jg * 4 + j] = fmaxf(acc[i][j] + bv[j], 0.f);
        }
    }
}

// ===========================================================================
// Fused mean-pool + MLP head (batch sorted -> contiguous ranges, no atomics)
// ===========================================================================
__global__ void pool_mlp_kernel(const float* __restrict__ x, const int* __restrict__ batch,
                                const float* __restrict__ W0, const float* __restrict__ b0,
                                const float* __restrict__ W1, const float* __restrict__ b1,
                                const float* __restrict__ W2, const float* __restrict__ b2,
                                float* __restrict__ out) {
    const int g = blockIdx.x;
    auto lb = [&](int key) {
        int lo = 0, hi = N_NODES;
        while (lo < hi) {
            int mid = (lo + hi) >> 1;
            if (batch[mid] < key) lo = mid + 1; else hi = mid;
        }
        return lo;
    };
    const int beg = lb(g), end = lb(g + 1);

    const int t = threadIdx.x;
    const int q = t & 7;
    const int r = t >> 3;

    float4 s = {0.f, 0.f, 0.f, 0.f};
    for (int n = beg + r; n < end; n += 32) {
        float4 v = *(reinterpret_cast<const float4*>(x + (size_t)n * 32) + q);
        s.x += v.x; s.y += v.y; s.z += v.z; s.w += v.w;
    }
    __shared__ float4 red[32][8];
    red[r][q] = s;
    __syncthreads();

    __shared__ float h0[32], h1[32], h2[16];
    if (r == 0) {
        float4 tot = {0.f, 0.f, 0.f, 0.f};
        #pragma unroll
        for (int i = 0; i < 32; ++i) {
            float4 v = red[i][q];
            tot.x += v.x; tot.y += v.y; tot.z += v.z; tot.w += v.w;
        }
        float c = fmaxf((float)(end - beg), 1.0f);
        h0[q * 4 + 0] = tot.x / c;
        h0[q * 4 + 1] = tot.y / c;
        h0[q * 4 + 2] = tot.z / c;
        h0[q * 4 + 3] = tot.w / c;
    }
    __syncthreads();
    if (t < 32) {
        float s1 = b0[t];
        for (int k = 0; k < 32; ++k) s1 += h0[k] * W0[k * 32 + t];
        h1[t] = fmaxf(s1, 0.f);
    }
    __syncthreads();
    if (t < 16) {
        float s2 = b1[t];
        for (int k = 0; k < 32; ++k) s2 += h1[k] * W1[k * 16 + t];
        h2[t] = fmaxf(s2, 0.f);
    }
    __syncthreads();
    if (t == 0) {
        float s3 = b2[0];
        for (int k = 0; k < 16; ++k) s3 += h2[k] * W2[k];
        out[g] = s3;
    }
}

// ===========================================================================
extern "C" void kernel_launch(void* const* d_in, const int* in_sizes, int n_in,
                              void* d_out, int out_size, void* d_ws, size_t ws_size,
                              hipStream_t stream) {
    const float* x_in  = (const float*)d_in[0];
    const int*   ei    = (const int*)d_in[1];
    const int*   src   = ei;
    const int*   dst   = ei + N_EDGES;
    const float* ew    = (const float*)d_in[2];
    const int*   batch = (const int*)d_in[3];

    const float* Wrel[5]  = {(const float*)d_in[4],  (const float*)d_in[7],  (const float*)d_in[10],
                             (const float*)d_in[13], (const float*)d_in[16]};
    const float* brel[5]  = {(const float*)d_in[5],  (const float*)d_in[8],  (const float*)d_in[11],
                             (const float*)d_in[14], (const float*)d_in[17]};
    const float* Wroot[5] = {(const float*)d_in[6],  (const float*)d_in[9],  (const float*)d_in[12],
                             (const float*)d_in[15], (const float*)d_in[18]};
    const float* mW0 = (const float*)d_in[19];
    const float* mb0 = (const float*)d_in[20];
    const float* mW1 = (const float*)d_in[21];
    const float* mb1 = (const float*)d_in[22];
    const float* mW2 = (const float*)d_in[23];
    const float* mb2 = (const float*)d_in[24];

    float* ws = (float*)d_ws;
    float* A = ws;                                 // [N,64]
    float* B = A + (size_t)N_NODES * 64;           // [N,128]
    float* C = B + (size_t)N_NODES * 128;          // [N,64]
    int*   rowptr = (int*)(C + (size_t)N_NODES * 64);   // N+1
    int*   cursor = rowptr + (N_NODES + 2);             // N
    int*   deg    = cursor + N_NODES;                   // N
    int*   bsum   = deg + N_NODES;                      // SCAN_NB
    int*   ssrc   = bsum + 128;                         // E
    float* sw     = (float*)(ssrc + N_EDGES);           // E

    const int BS = 256;
    auto blocks = [](long long total, int bs) { return (int)((total + bs - 1) / bs); };

    // ---- CSR build
    hipMemsetAsync(deg, 0, N_NODES * sizeof(int), stream);
    hist_kernel<<<blocks(N_EDGES, BS), BS, 0, stream>>>(dst, deg);
    scan_p1_kernel<<<SCAN_NB, SCAN_BS, 0, stream>>>(deg, bsum);
    scan_p2_kernel<<<1, 128, 0, stream>>>(bsum, rowptr);
    scan_p3_kernel<<<SCAN_NB, SCAN_BS, 0, stream>>>(deg, bsum, rowptr, cursor);
    fill_kernel<<<blocks(N_EDGES, BS), BS, 0, stream>>>(src, dst, ew, cursor, ssrc, sw);

    const int G64  = (N_NODES + 63) / 64;    // TN=64 grids
    const int G128 = (N_NODES + 127) / 128;  // TN=128 grids

    // ---- Layer 0: 5 -> 32.  gather(x_in) -> C, conv -> B[N,32]
    gather5_kernel<<<blocks(N_NODES, BS), BS, 0, stream>>>(rowptr, ssrc, sw, x_in, C);
    conv_out_kernel<5, 32><<<blocks(N_NODES, 128), BS, 0, stream>>>(C, x_in, Wrel[0], brel[0], Wroot[0], B);

    // ---- Layer 1: 32 -> 64.  gather(B,w32) -> C, GEMM -> A[N,64]   (TN=128)
    gather_kernel<32, false><<<blocks(N_NODES, 32), BS, 0, stream>>>(rowptr, ssrc, sw, B, nullptr, nullptr, C);
    gemm_kernel<32, 64, false><<<G128, 256, 0, stream>>>(C, B, Wrel[1], Wroot[1], brel[1], A, nullptr);

    // ---- Layer 2: 64 -> 128. gather(A,w64) -> C, GEMM -> B[N,128]  (TN=64)
    gather_kernel<64, false><<<blocks(N_NODES, 16), BS, 0, stream>>>(rowptr, ssrc, sw, A, nullptr, nullptr, C);
    gemm_kernel<64, 128, false><<<G64, 256, 0, stream>>>(C, A, Wrel[2], Wroot[2], brel[2], B, nullptr);

    // ---- Layer 3: 128 -> 64. dual GEMM: y=C, r=A; fused gather -> B[N,64]  (TN=64)
    gemm_kernel<128, 64, true><<<G64, 256, 0, stream>>>(B, nullptr, Wrel[3], Wroot[3], nullptr, C, A);
    gather_kernel<64, true><<<blocks(N_NODES, 16), BS, 0, stream>>>(rowptr, ssrc, sw, C, A, brel[3], B);

    // ---- Layer 4: 64 -> 32.  dual GEMM: y=C, r=A; fused gather -> B[N,32]  (TN=128)
    gemm_kernel<64, 32, true><<<G128, 256, 0, stream>>>(B, nullptr, Wrel[4], Wroot[4], nullptr, C, A);
    gather_kernel<32, true><<<blocks(N_NODES, 32), BS, 0, stream>>>(rowptr, ssrc, sw, C, A, brel[4], B);

    // ---- Fused mean pool + MLP
    pool_mlp_kernel<<<NUM_GRAPHS, 256, 0, stream>>>(B, batch, mW0, mb0, mW1, mb1, mW2, mb2, (float*)d_out);
}

// Round 10
// 359.100 us; speedup vs baseline: 16.1346x; 1.9010x over previous
//
#include <hip/hip_runtime.h>

#define N_NODES 100000
#define N_EDGES 600000
#define NUM_GRAPHS 256

#define SCAN_BS   256
#define SCAN_CH   4
#define SCAN_CHUNK (SCAN_BS * SCAN_CH)                      // 1024
#define SCAN_NB   ((N_NODES + SCAN_CHUNK - 1) / SCAN_CHUNK) // 98

// ===========================================================================
// CSR build: histogram -> 3-phase scan -> fill (once per launch, reused 5x)
// ===========================================================================
__global__ void hist_kernel(const int* __restrict__ dst, int* __restrict__ deg) {
    int e = blockIdx.x * blockDim.x + threadIdx.x;
    if (e < N_EDGES) atomicAdd(&deg[dst[e]], 1);
}

__global__ void scan_p1_kernel(const int* __restrict__ deg, int* __restrict__ bsum) {
    __shared__ int sh[SCAN_BS];
    const int b = blockIdx.x, t = threadIdx.x;
    const int base = b * SCAN_CHUNK + t * SCAN_CH;
    int s = 0;
    #pragma unroll
    for (int k = 0; k < SCAN_CH; ++k) {
        int i = base + k;
        if (i < N_NODES) s += deg[i];
    }
    sh[t] = s;
    __syncthreads();
    for (int off = SCAN_BS / 2; off > 0; off >>= 1) {
        if (t < off) sh[t] += sh[t + off];
        __syncthreads();
    }
    if (t == 0) bsum[b] = sh[0];
}

__global__ void scan_p2_kernel(int* __restrict__ bsum, int* __restrict__ rowptr) {
    __shared__ int sh[128];
    const int t = threadIdx.x;
    int v = (t < SCAN_NB) ? bsum[t] : 0;
    sh[t] = v;
    __syncthreads();
    for (int off = 1; off < 128; off <<= 1) {
        int u = (t >= off) ? sh[t - off] : 0;
        __syncthreads();
        sh[t] += u;
        __syncthreads();
    }
    if (t < SCAN_NB) bsum[t] = sh[t] - v;
    if (t == 0) rowptr[N_NODES] = N_EDGES;
}

__global__ void scan_p3_kernel(const int* __restrict__ deg, const int* __restrict__ bsum,
                               int* __restrict__ rowptr, int* __restrict__ cursor) {
    __shared__ int sh[SCAN_BS];
    const int b = blockIdx.x, t = threadIdx.x;
    const int base = b * SCAN_CHUNK + t * SCAN_CH;
    int v[SCAN_CH];
    int s = 0;
    #pragma unroll
    for (int k = 0; k < SCAN_CH; ++k) {
        int i = base + k;
        v[k] = (i < N_NODES) ? deg[i] : 0;
        s += v[k];
    }
    sh[t] = s;
    __syncthreads();
    for (int off = 1; off < SCAN_BS; off <<= 1) {
        int u = (t >= off) ? sh[t - off] : 0;
        __syncthreads();
        sh[t] += u;
        __syncthreads();
    }
    int run = bsum[b] + sh[t] - s;
    #pragma unroll
    for (int k = 0; k < SCAN_CH; ++k) {
        int i = base + k;
        if (i < N_NODES) { rowptr[i] = run; cursor[i] = run; }
        run += v[k];
    }
}

__global__ void fill_kernel(const int* __restrict__ src, const int* __restrict__ dst,
                            const float* __restrict__ w, int* __restrict__ cursor,
                            int* __restrict__ ssrc, float* __restrict__ sw) {
    int e = blockIdx.x * blockDim.x + threadIdx.x;
    if (e >= N_EDGES) return;
    int pos = atomicAdd(&cursor[dst[e]], 1);
    ssrc[pos] = src[e];
    sw[pos] = w[e];
}

// ===========================================================================
// CSR gather-aggregate, 4x unrolled edge loop
// ===========================================================================
template<int F, bool FUSED>
__global__ void gather_kernel(const int* __restrict__ rowptr, const int* __restrict__ ssrc,
                              const float* __restrict__ sw, const float* __restrict__ y,
                              const float* __restrict__ r, const float* __restrict__ b,
                              float* __restrict__ out) {
    constexpr int G = F / 4;
    constexpr int NPB = 256 / G;
    const int tid = threadIdx.x;
    const int c = tid % G;
    const int ln = tid / G;
    const int n = blockIdx.x * NPB + ln;
    if (n >= N_NODES) return;
    const int beg = rowptr[n], end = rowptr[n + 1];
    float4 acc = {0.f, 0.f, 0.f, 0.f};
    int i = beg;
    for (; i + 3 < end; i += 4) {
        int s0 = ssrc[i], s1 = ssrc[i + 1], s2 = ssrc[i + 2], s3 = ssrc[i + 3];
        float w0 = sw[i], w1 = sw[i + 1], w2 = sw[i + 2], w3 = sw[i + 3];
        float4 v0 = *(reinterpret_cast<const float4*>(y + (size_t)s0 * F) + c);
        float4 v1 = *(reinterpret_cast<const float4*>(y + (size_t)s1 * F) + c);
        float4 v2 = *(reinterpret_cast<const float4*>(y + (size_t)s2 * F) + c);
        float4 v3 = *(reinterpret_cast<const float4*>(y + (size_t)s3 * F) + c);
        acc.x += v0.x * w0 + v1.x * w1 + v2.x * w2 + v3.x * w3;
        acc.y += v0.y * w0 + v1.y * w1 + v2.y * w2 + v3.y * w3;
        acc.z += v0.z * w0 + v1.z * w1 + v2.z * w2 + v3.z * w3;
        acc.w += v0.w * w0 + v1.w * w1 + v2.w * w2 + v3.w * w3;
    }
    for (; i < end; ++i) {
        int s0 = ssrc[i];
        float w0 = sw[i];
        float4 v0 = *(reinterpret_cast<const float4*>(y + (size_t)s0 * F) + c);
        acc.x += v0.x * w0; acc.y += v0.y * w0; acc.z += v0.z * w0; acc.w += v0.w * w0;
    }
    if constexpr (FUSED) {
        float4 rv = *(reinterpret_cast<const float4*>(r + (size_t)n * F) + c);
        float4 bv = *(reinterpret_cast<const float4*>(b) + c);
        acc.x = fmaxf(acc.x + rv.x + bv.x, 0.f);
        acc.y = fmaxf(acc.y + rv.y + bv.y, 0.f);
        acc.z = fmaxf(acc.z + rv.z + bv.z, 0.f);
        acc.w = fmaxf(acc.w + rv.w + bv.w, 0.f);
    }
    *(reinterpret_cast<float4*>(out + (size_t)n * F) + c) = acc;
}

__global__ void gather5_kernel(const int* __restrict__ rowptr, const int* __restrict__ ssrc,
                               const float* __restrict__ sw, const float* __restrict__ x,
                               float* __restrict__ agg) {
    int n = blockIdx.x * blockDim.x + threadIdx.x;
    if (n >= N_NODES) return;
    float a0 = 0.f, a1 = 0.f, a2 = 0.f, a3 = 0.f, a4 = 0.f;
    for (int i = rowptr[n]; i < rowptr[n + 1]; ++i) {
        int s = ssrc[i];
        float we = sw[i];
        const float* xs = x + (size_t)s * 5;
        a0 += xs[0] * we; a1 += xs[1] * we; a2 += xs[2] * we;
        a3 += xs[3] * we; a4 += xs[4] * we;
    }
    float* o = agg + (size_t)n * 5;
    o[0] = a0; o[1] = a1; o[2] = a2; o[3] = a3; o[4] = a4;
}

// ===========================================================================
// Pipelined LDS-tiled GEMM — EXACT R7 structure (proven: 84 VGPR, no spill,
// no bank conflicts, VALUBusy 57%). 8 nodes x 4 cols per thread; explicit
// register ping-pong (aA/wA, aB/wB); runtime-k0 steady loop.
//  DUAL=false (conv): out1 = relu([in1|in2] @ [Wrel;Wroot] + brel)  (K = 2*FIN)
//  DUAL=true:         out1 = in1@Wrel ; out2 = in1@Wroot            (K = FIN)
// ===========================================================================
template<int FIN, int FOUT, bool DUAL>
__global__ __launch_bounds__(256, 3)
void gemm_kernel(const float* __restrict__ in1, const float* __restrict__ in2,
                 const float* __restrict__ Wrel, const float* __restrict__ Wroot,
                 const float* __restrict__ brel,
                 float* __restrict__ out1, float* __restrict__ out2) {
    constexpr int KT = DUAL ? FIN : 2 * FIN;            // total K
    constexpr int JG = DUAL ? (FOUT / 2) : (FOUT / 4);  // float4 col-groups
    constexpr int NG = 256 / JG;
    constexpr int TN = NG * 8;                          // nodes per block
    constexpr int CH = KT / 4;                          // float4 chunks per row
    constexpr int C1 = FIN / 4;                         // chunks from in1
    constexpr int TOT = TN * CH;                        // = 2048 for all four

    __shared__ float smem[TN * KT];                     // 32 KB

    const int tid = threadIdx.x;
    const int n0 = blockIdx.x * TN;
    const bool full = (n0 + TN <= N_NODES);

    // ---- stage tile (rows: [in1 | in2] for conv)
    #pragma unroll
    for (int r2 = 0; r2 < TOT / 256; ++r2) {
        int idx = r2 * 256 + tid;
        int n = idx / CH, c = idx - n * CH;
        int gn = n0 + n;
        float4 v = {0.f, 0.f, 0.f, 0.f};
        if (full || gn < N_NODES) {
            if constexpr (DUAL) {
                v = *(const float4*)(in1 + (size_t)gn * FIN + c * 4);
            } else {
                v = (c < C1) ? *(const float4*)(in1 + (size_t)gn * FIN + c * 4)
                             : *(const float4*)(in2 + (size_t)gn * FIN + (c - C1) * 4);
            }
        }
        *(float4*)(smem + n * KT + c * 4) = v;
    }
    __syncthreads();

    const int jg = tid % JG;
    const int ng = tid / JG;
    const float* sA = smem + (ng * 8) * KT;

    const float* pW1;       // weight base for k < FIN
    const float* pW2;       // base for k >= FIN, pre-shifted so +k*FOUT works
    float* outd = out1;
    int col;
    if constexpr (DUAL) {
        const bool second = jg >= (FOUT / 4);
        pW1 = second ? Wroot : Wrel;
        pW2 = pW1;
        outd = second ? out2 : out1;
        col = (second ? jg - FOUT / 4 : jg) * 4;
    } else {
        pW1 = Wrel;
        pW2 = Wroot - (ptrdiff_t)FIN * FOUT;   // pW2 + k*FOUT == Wroot + (k-FIN)*FOUT
        col = jg * 4;
    }

    float acc[8][4] = {};
    float4 aA[8], aB[8], wA[4], wB[4];

    auto wrow = [&](int k) -> float4 {
        const float* base = (DUAL || k < FIN) ? pW1 : pW2;
        return *(const float4*)(base + (ptrdiff_t)k * FOUT + col);
    };

#define LOADT(A_, W_, K0)                                         \
    { _Pragma("unroll") for (int i = 0; i < 8; ++i)               \
          A_[i] = *(const float4*)(sA + i * KT + (K0));           \
      W_[0] = wrow((K0) + 0); W_[1] = wrow((K0) + 1);             \
      W_[2] = wrow((K0) + 2); W_[3] = wrow((K0) + 3); }

#define FMAT(A_, W_)                                                        \
    { _Pragma("unroll") for (int i = 0; i < 8; ++i) {                       \
        acc[i][0] += A_[i].x * W_[0].x; acc[i][1] += A_[i].x * W_[0].y;     \
        acc[i][2] += A_[i].x * W_[0].z; acc[i][3] += A_[i].x * W_[0].w;     \
        acc[i][0] += A_[i].y * W_[1].x; acc[i][1] += A_[i].y * W_[1].y;     \
        acc[i][2] += A_[i].y * W_[1].z; acc[i][3] += A_[i].y * W_[1].w;     \
        acc[i][0] += A_[i].z * W_[2].x; acc[i][1] += A_[i].z * W_[2].y;     \
        acc[i][2] += A_[i].z * W_[2].z; acc[i][3] += A_[i].z * W_[2].w;     \
        acc[i][0] += A_[i].w * W_[3].x; acc[i][1] += A_[i].w * W_[3].y;     \
        acc[i][2] += A_[i].w * W_[3].z; acc[i][3] += A_[i].w * W_[3].w; } }

    // prologue: groups 0 and 4 in flight
    LOADT(aA, wA, 0);
    LOADT(aB, wB, 4);
    // steady state: compute k0,k0+4 while prefetching k0+8,k0+12
    #pragma unroll 1
    for (int k0 = 0; k0 < KT - 8; k0 += 8) {
        FMAT(aA, wA);
        LOADT(aA, wA, k0 + 8);
        FMAT(aB, wB);
        LOADT(aB, wB, k0 + 12);
    }
    FMAT(aA, wA);
    FMAT(aB, wB);

#undef LOADT
#undef FMAT

    // ---- write
    if constexpr (DUAL) {
        #pragma unroll
        for (int i = 0; i < 8; ++i) {
            int n = n0 + ng * 8 + i;
            if (full || n < N_NODES) {
                float4 o = {acc[i][0], acc[i][1], acc[i][2], acc[i][3]};
                *(float4*)(outd + (size_t)n * FOUT + col) = o;
            }
        }
    } else {
        float4 b4 = *(const float4*)(brel + col);
        #pragma unroll
        for (int i = 0; i < 8; ++i) {
            int n = n0 + ng * 8 + i;
            if (full || n < N_NODES) {
                float4 o = {fmaxf(acc[i][0] + b4.x, 0.f), fmaxf(acc[i][1] + b4.y, 0.f),
                            fmaxf(acc[i][2] + b4.z, 0.f), fmaxf(acc[i][3] + b4.w, 0.f)};
                *(float4*)(out1 + (size_t)n * FOUT + col) = o;
            }
        }
    }
}

// ===========================================================================
// Layer-0 conv (FIN=5): simple register-tiled version
// ===========================================================================
template<int FIN, int FOUT>
__global__ void conv_out_kernel(const float* __restrict__ agg, const float* __restrict__ x,
                                const float* __restrict__ Wrel, const float* __restrict__ brel,
                                const float* __restrict__ Wroot, float* __restrict__ out) {
    constexpr int JG = FOUT / 4;
    constexpr int NG = 256 / JG;
    constexpr int NT = NG * 4;
    const int tid = threadIdx.x;
    const int jg = tid % JG;
    const int ng = tid / JG;
    const int n0 = blockIdx.x * NT + ng * 4;

    float acc[4][4] = {};
    for (int k = 0; k < FIN; ++k) {
        float a[4], xx[4];
        #pragma unroll
        for (int i = 0; i < 4; ++i) {
            int n = n0 + i;
            a[i]  = (n < N_NODES) ? agg[(size_t)n * FIN + k] : 0.f;
            xx[i] = (n < N_NODES) ? x[(size_t)n * FIN + k]   : 0.f;
        }
        float4 wr = *reinterpret_cast<const float4*>(Wrel  + (size_t)k * FOUT + jg * 4);
        float4 wo = *reinterpret_cast<const float4*>(Wroot + (size_t)k * FOUT + jg * 4);
        float wrv[4] = {wr.x, wr.y, wr.z, wr.w};
        float wov[4] = {wo.x, wo.y, wo.z, wo.w};
        #pragma unroll
        for (int i = 0; i < 4; ++i)
            #pragma unroll
            for (int j = 0; j < 4; ++j)
                acc[i][j] += a[i] * wrv[j] + xx[i] * wov[j];
    }
    float4 b4 = *reinterpret_cast<const float4*>(brel + jg * 4);
    float bv[4] = {b4.x, b4.y, b4.z, b4.w};
    #pragma unroll
    for (int i = 0; i < 4; ++i) {
        int n = n0 + i;
        if (n < N_NODES) {
            #pragma unroll
            for (int j = 0; j < 4; ++j)
                out[(size_t)n * FOUT + jg * 4 + j] = fmaxf(acc[i][j] + bv[j], 0.f);
        }
    }
}

// ===========================================================================
// Fused mean-pool + MLP head (batch sorted -> contiguous ranges, no atomics)
// ===========================================================================
__global__ void pool_mlp_kernel(const float* __restrict__ x, const int* __restrict__ batch,
                                const float* __restrict__ W0, const float* __restrict__ b0,
                                const float* __restrict__ W1, const float* __restrict__ b1,
                                const float* __restrict__ W2, const float* __restrict__ b2,
                                float* __restrict__ out) {
    const int g = blockIdx.x;
    auto lb = [&](int key) {
        int lo = 0, hi = N_NODES;
        while (lo < hi) {
            int mid = (lo + hi) >> 1;
            if (batch[mid] < key) lo = mid + 1; else hi = mid;
        }
        return lo;
    };
    const int beg = lb(g), end = lb(g + 1);

    const int t = threadIdx.x;
    const int q = t & 7;
    const int r = t >> 3;

    float4 s = {0.f, 0.f, 0.f, 0.f};
    for (int n = beg + r; n < end; n += 32) {
        float4 v = *(reinterpret_cast<const float4*>(x + (size_t)n * 32) + q);
        s.x += v.x; s.y += v.y; s.z += v.z; s.w += v.w;
    }
    __shared__ float4 red[32][8];
    red[r][q] = s;
    __syncthreads();

    __shared__ float h0[32], h1[32], h2[16];
    if (r == 0) {
        float4 tot = {0.f, 0.f, 0.f, 0.f};
        #pragma unroll
        for (int i = 0; i < 32; ++i) {
            float4 v = red[i][q];
            tot.x += v.x; tot.y += v.y; tot.z += v.z; tot.w += v.w;
        }
        float c = fmaxf((float)(end - beg), 1.0f);
        h0[q * 4 + 0] = tot.x / c;
        h0[q * 4 + 1] = tot.y / c;
        h0[q * 4 + 2] = tot.z / c;
        h0[q * 4 + 3] = tot.w / c;
    }
    __syncthreads();
    if (t < 32) {
        float s1 = b0[t];
        for (int k = 0; k < 32; ++k) s1 += h0[k] * W0[k * 32 + t];
        h1[t] = fmaxf(s1, 0.f);
    }
    __syncthreads();
    if (t < 16) {
        float s2 = b1[t];
        for (int k = 0; k < 32; ++k) s2 += h1[k] * W1[k * 16 + t];
        h2[t] = fmaxf(s2, 0.f);
    }
    __syncthreads();
    if (t == 0) {
        float s3 = b2[0];
        for (int k = 0; k < 16; ++k) s3 += h2[k] * W2[k];
        out[g] = s3;
    }
}

// ===========================================================================
extern "C" void kernel_launch(void* const* d_in, const int* in_sizes, int n_in,
                              void* d_out, int out_size, void* d_ws, size_t ws_size,
                              hipStream_t stream) {
    const float* x_in  = (const float*)d_in[0];
    const int*   ei    = (const int*)d_in[1];
    const int*   src   = ei;
    const int*   dst   = ei + N_EDGES;
    const float* ew    = (const float*)d_in[2];
    const int*   batch = (const int*)d_in[3];

    const float* Wrel[5]  = {(const float*)d_in[4],  (const float*)d_in[7],  (const float*)d_in[10],
                             (const float*)d_in[13], (const float*)d_in[16]};
    const float* brel[5]  = {(const float*)d_in[5],  (const float*)d_in[8],  (const float*)d_in[11],
                             (const float*)d_in[14], (const float*)d_in[17]};
    const float* Wroot[5] = {(const float*)d_in[6],  (const float*)d_in[9],  (const float*)d_in[12],
                             (const float*)d_in[15], (const float*)d_in[18]};
    const float* mW0 = (const float*)d_in[19];
    const float* mb0 = (const float*)d_in[20];
    const float* mW1 = (const float*)d_in[21];
    const float* mb1 = (const float*)d_in[22];
    const float* mW2 = (const float*)d_in[23];
    const float* mb2 = (const float*)d_in[24];

    float* ws = (float*)d_ws;
    float* A = ws;                                 // [N,64]
    float* B = A + (size_t)N_NODES * 64;           // [N,128]
    float* C = B + (size_t)N_NODES * 128;          // [N,64]
    int*   rowptr = (int*)(C + (size_t)N_NODES * 64);   // N+1
    int*   cursor = rowptr + (N_NODES + 2);             // N
    int*   deg    = cursor + N_NODES;                   // N
    int*   bsum   = deg + N_NODES;                      // SCAN_NB
    int*   ssrc   = bsum + 128;                         // E
    float* sw     = (float*)(ssrc + N_EDGES);           // E

    const int BS = 256;
    auto blocks = [](long long total, int bs) { return (int)((total + bs - 1) / bs); };

    // ---- CSR build
    hipMemsetAsync(deg, 0, N_NODES * sizeof(int), stream);
    hist_kernel<<<blocks(N_EDGES, BS), BS, 0, stream>>>(dst, deg);
    scan_p1_kernel<<<SCAN_NB, SCAN_BS, 0, stream>>>(deg, bsum);
    scan_p2_kernel<<<1, 128, 0, stream>>>(bsum, rowptr);
    scan_p3_kernel<<<SCAN_NB, SCAN_BS, 0, stream>>>(deg, bsum, rowptr, cursor);
    fill_kernel<<<blocks(N_EDGES, BS), BS, 0, stream>>>(src, dst, ew, cursor, ssrc, sw);

    const int G64  = (N_NODES + 63) / 64;    // TN=64 grids
    const int G128 = (N_NODES + 127) / 128;  // TN=128 grids

    // ---- Layer 0: 5 -> 32.  gather(x_in) -> C, conv -> B[N,32]
    gather5_kernel<<<blocks(N_NODES, BS), BS, 0, stream>>>(rowptr, ssrc, sw, x_in, C);
    conv_out_kernel<5, 32><<<blocks(N_NODES, 128), BS, 0, stream>>>(C, x_in, Wrel[0], brel[0], Wroot[0], B);

    // ---- Layer 1: 32 -> 64.  gather(B,w32) -> C, GEMM -> A[N,64]   (TN=128)
    gather_kernel<32, false><<<blocks(N_NODES, 32), BS, 0, stream>>>(rowptr, ssrc, sw, B, nullptr, nullptr, C);
    gemm_kernel<32, 64, false><<<G128, 256, 0, stream>>>(C, B, Wrel[1], Wroot[1], brel[1], A, nullptr);

    // ---- Layer 2: 64 -> 128. gather(A,w64) -> C, GEMM -> B[N,128]  (TN=64)
    gather_kernel<64, false><<<blocks(N_NODES, 16), BS, 0, stream>>>(rowptr, ssrc, sw, A, nullptr, nullptr, C);
    gemm_kernel<64, 128, false><<<G64, 256, 0, stream>>>(C, A, Wrel[2], Wroot[2], brel[2], B, nullptr);

    // ---- Layer 3: 128 -> 64. dual GEMM: y=C, r=A; fused gather -> B[N,64]  (TN=64)
    gemm_kernel<128, 64, true><<<G64, 256, 0, stream>>>(B, nullptr, Wrel[3], Wroot[3], nullptr, C, A);
    gather_kernel<64, true><<<blocks(N_NODES, 16), BS, 0, stream>>>(rowptr, ssrc, sw, C, A, brel[3], B);

    // ---- Layer 4: 64 -> 32.  dual GEMM: y=C, r=A; fused gather -> B[N,32]  (TN=128)
    gemm_kernel<64, 32, true><<<G128, 256, 0, stream>>>(B, nullptr, Wrel[4], Wroot[4], nullptr, C, A);
    gather_kernel<32, true><<<blocks(N_NODES, 32), BS, 0, stream>>>(rowptr, ssrc, sw, C, A, brel[4], B);

    // ---- Fused mean pool + MLP
    pool_mlp_kernel<<<NUM_GRAPHS, 256, 0, stream>>>(B, batch, mW0, mb0, mW1, mb1, mW2, mb2, (float*)d_out);
}